// Round 5
// baseline (31.329 us; speedup 1.0000x reference)
//
#include <hip/hip_runtime.h>
#include <hip/hip_bf16.h>

// Problem dims (fixed by setup_inputs)
#define BS     256
#define N_BAG  128
#define DXD    32
#define DYD    10
#define M_COMP 2048
#define CHUNKS 8              // m-chunks per batch row; 256 m's per block

typedef __attribute__((ext_vector_type(8))) short short8v;   // 8 bf16 (4 VGPRs)
typedef __attribute__((ext_vector_type(4))) float f32x4;

static __device__ __forceinline__ unsigned int pkbf(float a, float b) {
    // RNE pack of two f32 -> 2x bf16 in one u32 (v_cvt_pk_bf16_f32)
    unsigned short ha = __bfloat16_as_ushort(__float2bfloat16(a));
    unsigned short hb = __bfloat16_as_ushort(__float2bfloat16(b));
    return (unsigned int)ha | ((unsigned int)hb << 16);
}
static __device__ __forceinline__ float fast_exp2(float x) {
#if __has_builtin(__builtin_amdgcn_exp2f)
    return __builtin_amdgcn_exp2f(x);
#else
    return __expf(x * 0.6931471805599453f);
#endif
}

// grid 2048 = (b, chunk); block 256 = 4 waves. Wave pair wp covers 8 m-tiles;
// within a pair, wave 'half' covers 4 of the 8 n-tiles. A' = (-2c2)*X in bf16,
// C seeded with c2*a2[row] + c2*b2[col]  ->  MFMA output == exponent e = c2*d2.
// K^2 = 2^e. Epilogue per element: exp2 + add. Projection done in phase 2.
__global__ __launch_bounds__(256, 8) void main_kernel(
    const float* __restrict__ X,        // (BS, N_BAG, DXD)
    const float* __restrict__ sig_p,    // scalar
    const float* __restrict__ c_x,      // (M_COMP, DXD)
    const float* __restrict__ c_y,      // (M_COMP, DYD)
    const float* __restrict__ comp_w,   // (M_COMP,)
    float* __restrict__ part)           // (2048, 16): [0]=wsum, [1..10]=probs partials
{
    __shared__ short8v Af[8][64];          // A' fragments, 8 n-tiles (8 KB)
    __shared__ float   a2part[N_BAG][4];
    __shared__ float   a2c[N_BAG];         // c2 * ||x_n||^2
    __shared__ float   ow_s[2][256];       // per-half csum per m
    __shared__ float   red[4][12];

    const int tid   = threadIdx.x;
    const int bid   = blockIdx.x;
    const int b     = bid >> 3;
    const int chunk = bid & 7;

    const float sgm = fmaxf(sig_p[0], 1e-3f);
    const float c2  = -1.4426950408889634f / (sgm * sgm);  // -log2(e)/sigma^2 (<0)
    const float sA  = -2.0f * c2;                          // A-side scale (>0)

    // ---- stage A' = sA*X as bf16 fragments + c2-scaled row norms ----
#pragma unroll
    for (int k = 0; k < 2; ++k) {
        const int u = tid + 256 * k;
        const int n = u >> 2, g4 = u & 3;
        const float4* Xr = (const float4*)(X + ((size_t)(b * N_BAG + n) * DXD + 8 * g4));
        float4 v0 = Xr[0], v1 = Xr[1];
        float s = 0.f;
        s = fmaf(v0.x, v0.x, s); s = fmaf(v0.y, v0.y, s);
        s = fmaf(v0.z, v0.z, s); s = fmaf(v0.w, v0.w, s);
        s = fmaf(v1.x, v1.x, s); s = fmaf(v1.y, v1.y, s);
        s = fmaf(v1.z, v1.z, s); s = fmaf(v1.w, v1.w, s);
        union { unsigned int u4[4]; short8v s8; } cv;
        cv.u4[0] = pkbf(sA * v0.x, sA * v0.y); cv.u4[1] = pkbf(sA * v0.z, sA * v0.w);
        cv.u4[2] = pkbf(sA * v1.x, sA * v1.y); cv.u4[3] = pkbf(sA * v1.z, sA * v1.w);
        Af[n >> 4][g4 * 16 + (n & 15)] = cv.s8;
        a2part[n][g4] = s;
    }
    __syncthreads();
    if (tid < N_BAG)
        a2c[tid] = c2 * (a2part[tid][0] + a2part[tid][1] +
                         a2part[tid][2] + a2part[tid][3]);
    __syncthreads();

    const int lane = tid & 63, wv = tid >> 6;
    const int half = wv & 1, wp = wv >> 1;
    const int r = lane & 15, gq = lane >> 4, rowg = gq * 4;

    // 4 A-fragments + 4 seed rows resident in VGPRs (n-half of the problem)
    short8v Xf[4];
    f32x4   s4[4];
#pragma unroll
    for (int j = 0; j < 4; ++j) {
        Xf[j] = Af[half * 4 + j][lane];
        s4[j] = *(const f32x4*)&a2c[(half * 4 + j) * 16 + rowg];
    }

    const int mt_base = chunk * 16 + wp * 8;
#pragma unroll
    for (int i = 0; i < 8; ++i) {
        const int m = (mt_base + i) * 16 + r;   // lane's c_x row = its C column
        const float4* cp4 = (const float4*)(c_x + (size_t)m * DXD + 8 * gq);
        float4 p0 = cp4[0], p1 = cp4[1];
        union { unsigned int u4[4]; short8v s8; } bc;
        bc.u4[0] = pkbf(p0.x, p0.y); bc.u4[1] = pkbf(p0.z, p0.w);
        bc.u4[2] = pkbf(p1.x, p1.y); bc.u4[3] = pkbf(p1.z, p1.w);
        float s = 0.f;
        s = fmaf(p0.x, p0.x, s); s = fmaf(p0.y, p0.y, s);
        s = fmaf(p0.z, p0.z, s); s = fmaf(p0.w, p0.w, s);
        s = fmaf(p1.x, p1.x, s); s = fmaf(p1.y, p1.y, s);
        s = fmaf(p1.z, p1.z, s); s = fmaf(p1.w, p1.w, s);
        s += __shfl_xor(s, 16, 64);
        s += __shfl_xor(s, 32, 64);             // b2[m] in every lane
        const float cbv = c2 * s;

        float cs0 = 0.f, cs1 = 0.f;
#pragma unroll
        for (int j = 0; j < 4; ++j) {
            f32x4 seed = s4[j] + cbv;           // c2*a2[row] + c2*b2[col]
            f32x4 acc  = __builtin_amdgcn_mfma_f32_16x16x32_bf16(Xf[j], bc.s8, seed, 0, 0, 0);
            cs0 += fast_exp2(acc[0]); cs1 += fast_exp2(acc[1]);
            cs0 += fast_exp2(acc[2]); cs1 += fast_exp2(acc[3]);
        }
        float csum = cs0 + cs1;
        csum += __shfl_xor(csum, 16, 64);
        csum += __shfl_xor(csum, 32, 64);       // sum over this wave's 64 n-rows
        if (lane < 16) ow_s[half][wp * 128 + i * 16 + r] = csum;
    }
    __syncthreads();

    // ---- phase 2: coalesced projection over this block's 256 m's ----
    {
        const int m = chunk * 256 + tid;
        const float w = (ow_s[0][tid] + ow_s[1][tid]) * comp_w[m] * (1.0f / N_BAG);
        const float2* cyp = (const float2*)(c_y + (size_t)m * DYD);
        float2 y0 = cyp[0], y1 = cyp[1], y2 = cyp[2], y3 = cyp[3], y4 = cyp[4];
        float cy[DYD] = {y0.x, y0.y, y1.x, y1.y, y2.x, y2.y, y3.x, y3.y, y4.x, y4.y};
        float ny = 0.f;
#pragma unroll
        for (int d = 0; d < DYD; ++d) ny = fmaf(cy[d], cy[d], ny);
        const float yw = w * __builtin_amdgcn_rcpf(ny);
        float vals[DYD + 1];
        vals[0] = w;
#pragma unroll
        for (int d = 0; d < DYD; ++d) vals[1 + d] = yw * cy[d] * cy[d];

#pragma unroll
        for (int v = 0; v <= DYD; ++v) {
            float x = vals[v];
#pragma unroll
            for (int off = 32; off > 0; off >>= 1) x += __shfl_down(x, off, 64);
            if (lane == 0) red[wv][v] = x;
        }
        __syncthreads();
        if (tid <= DYD)
            part[(size_t)bid * 16 + tid] = red[0][tid] + red[1][tid] + red[2][tid] + red[3][tid];
    }
}

// ---- combine: 1 block, 1024 threads; 4 threads per b sum 8 chunk-partials ----
__global__ __launch_bounds__(1024) void combine_kernel(const float* __restrict__ part,
                                                       float* __restrict__ out) {
    const int t = threadIdx.x;
    const int b = t >> 2, q = t & 3;
    float s[DYD + 1];
#pragma unroll
    for (int v = 0; v <= DYD; ++v) s[v] = 0.f;
#pragma unroll
    for (int c = 0; c < 2; ++c) {
        const float* p = part + (size_t)(b * 8 + q + 4 * c) * 16;
#pragma unroll
        for (int v = 0; v <= DYD; ++v) s[v] += p[v];
    }
#pragma unroll
    for (int v = 0; v <= DYD; ++v) {
        s[v] += __shfl_xor(s[v], 1, 64);
        s[v] += __shfl_xor(s[v], 2, 64);
    }
    if (q == 0) {
        float d = s[0];
        d = (d == 0.f) ? 1e-16f : d;
        const float inv = 1.0f / d;
#pragma unroll
        for (int dd = 0; dd < DYD; ++dd)
            out[(size_t)b * DYD + dd] = s[1 + dd] * inv;
    }
}

extern "C" void kernel_launch(void* const* d_in, const int* in_sizes, int n_in,
                              void* d_out, int out_size, void* d_ws, size_t ws_size,
                              hipStream_t stream) {
    const float* X      = (const float*)d_in[0];  // (256,128,32)
    const float* sigma  = (const float*)d_in[1];  // scalar
    const float* c_x    = (const float*)d_in[2];  // (2048,32)
    const float* c_y    = (const float*)d_in[3];  // (2048,10)
    const float* comp_w = (const float*)d_in[4];  // (2048,)
    float*       out    = (float*)d_out;          // (256,10)

    float* part = (float*)d_ws;                   // 2048*16 floats = 128 KB

    main_kernel<<<BS * CHUNKS, 256, 0, stream>>>(X, sigma, c_x, c_y, comp_w, part);
    combine_kernel<<<1, 1024, 0, stream>>>(part, out);
}